// Round 6
// baseline (32.558 us; speedup 1.0000x reference)
//
#include <hip/hip_runtime.h>

typedef __attribute__((ext_vector_type(8))) short bf16x8;
typedef __attribute__((ext_vector_type(4))) float f32x4;

constexpr int NCH = 18;     // 32-k chunks per K-quarter (K=2304 symmetrized)

__device__ __forceinline__ unsigned short bf_rne(float f) {
  unsigned u = __float_as_uint(f);
  return (unsigned short)((u + 0x7fffu + ((u >> 16) & 1u)) >> 16);
}

// ---- prepass: symmetrize + pack W fragment-linear for the (kq, nh) wave split ----
// Wp ushort index e = ((((kq*18 + j)*2 + nh)*2 + nt2)*64 + lane)*8 + el
// holds W_sym[o = nh*32 + nt2*16 + (lane&15)][k = kq*576 + j*32 + (lane>>4)*8 + el]
__global__ __launch_bounds__(256) void wprep_kernel(const float* __restrict__ W,
                                                    unsigned short* __restrict__ Wp) {
  int e = blockIdx.x * 256 + threadIdx.x;   // 576 blocks * 256 = 147456
  int el = e & 7;
  int lane = (e >> 3) & 63;
  int nt2 = (e >> 9) & 1;
  int nh = (e >> 10) & 1;
  int jj = e >> 11;            // 0..71
  int kq = jj / 18;
  int j = jj - kq * 18;
  int q = lane >> 4, r16 = lane & 15;
  int o = nh * 32 + nt2 * 16 + r16;
  int kl = j * 32 + q * 8 + el;            // k within quarter
  int jblk = kl >> 6, i = kl & 63;
  int run1 = 8 - kq;
  int G, F;
  if (jblk < run1) { G = 7 - kq; F = jblk; } else { G = kq; F = jblk - run1; }
  int f = F * 8 + (i >> 3), g = G * 8 + (i & 7);
  float v = W[o * 4096 + f * 64 + g];
  if (F != G) v += W[o * 4096 + g * 64 + f];
  Wp[e] = bf_rne(v);
}

// ---- main: 256 blocks x 512 thr (8 waves = 4 kq x 2 nh), 128 px/block ----
// Each wave owns (K-quarter, o-half): block reads W exactly once (288 KB/CU).
// B streamed to a 5-slot register ring (lead 4 j-computes ~ 760 cyc).
__global__ __launch_bounds__(512, 2) void quad_kernel(const float* __restrict__ x,
                                                      const unsigned short* __restrict__ Wp,
                                                      float* __restrict__ out) {
  __shared__ float xT[8192];                 // [f 64][px 128], word = f*128 + (px^f)  (32 KB)
  __shared__ alignas(16) float red[8192];    // epilogue reduction (32 KB)

  const int t = threadIdx.x;
  const int lane = t & 63;
  const int wv = t >> 6;        // 0..7
  const int kq = wv & 3;        // K quarter
  const int nh = wv >> 2;       // o half
  const int q = lane >> 4;
  const int r16 = lane & 15;
  const int pxbase = blockIdx.x * 128;

  // fragment-linear B source for this wave
  const char* wsrc = reinterpret_cast<const char*>(Wp) + kq * 73728 + nh * 2048 + lane * 16;

  bf16x8 bufs[5][2];
  auto loadB = [&](int j, int slot) {
    bufs[slot][0] = *reinterpret_cast<const bf16x8*>(wsrc + j * 4096);
    bufs[slot][1] = *reinterpret_cast<const bf16x8*>(wsrc + j * 4096 + 1024);
  };
  loadB(0, 0); loadB(1, 1); loadB(2, 2); loadB(3, 3);

  // x tile -> xT (transposed, XOR word-swizzle; verified r3-r5)
  {
    const float* xg_ = x + (long)pxbase * 64;
#pragma unroll
    for (int c = 0; c < 4; ++c) {
      int e4 = c * 512 + t;
      int px = e4 >> 4;            // 0..127
      int f0 = (e4 & 15) * 4;
      float4 v = *reinterpret_cast<const float4*>(xg_ + e4 * 4);
      xT[(f0 + 0) * 128 + (px ^ (f0 + 0))] = v.x;
      xT[(f0 + 1) * 128 + (px ^ (f0 + 1))] = v.y;
      xT[(f0 + 2) * 128 + (px ^ (f0 + 2))] = v.z;
      xT[(f0 + 3) * 128 + (px ^ (f0 + 3))] = v.w;
    }
  }
  __syncthreads();

  float xg[8][8];
  auto load_xg = [&](int G) {
#pragma unroll
    for (int m = 0; m < 8; ++m) {
      int px = m * 16 + r16;
#pragma unroll
      for (int b = 0; b < 8; ++b) {
        int row = G * 8 + b;
        xg[m][b] = xT[row * 128 + (px ^ row)];
      }
    }
  };
  const int run1 = 8 - kq;
  load_xg(7 - kq);

  f32x4 acc[8][2] = {};   // [m: 8x16 px][nt2: 2x16 o]

#pragma unroll
  for (int j = 0; j < NCH; ++j) {
    if (j + 4 < NCH) loadB(j + 4, (j + 4) % 5);   // refill ahead (slot != j%5)
    if (j == 2 * run1) load_xg(kq);               // wave-uniform G-run switch
    const int s = j & 1;
    const int blk = j >> 1;
    const int F = (blk < run1) ? blk : blk - run1;
    const int row = F * 8 + s * 4 + q;
    const int slot = j % 5;
#pragma unroll
    for (int m = 0; m < 8; ++m) {
      float xf = xT[row * 128 + ((m * 16 + r16) ^ row)];
      union { unsigned u[4]; bf16x8 v; } pk;
#pragma unroll
      for (int i = 0; i < 4; ++i) {
        unsigned p0 = __float_as_uint(xf * xg[m][2 * i]);
        unsigned p1 = __float_as_uint(xf * xg[m][2 * i + 1]);
        pk.u[i] = __builtin_amdgcn_perm(p1, p0, 0x07060302u);   // truncate-pack 2x bf16
      }
      acc[m][0] = __builtin_amdgcn_mfma_f32_16x16x32_bf16(pk.v, bufs[slot][0], acc[m][0], 0, 0, 0);
      acc[m][1] = __builtin_amdgcn_mfma_f32_16x16x32_bf16(pk.v, bufs[slot][1], acc[m][1], 0, 0, 0);
    }
  }

  // ---- cross-kq reduction: 4 rounds of m-pairs through 32 KB red ----
  // region(mm, kq) = 4 KB: [o 64][px_local 16] floats
#pragma unroll
  for (int r = 0; r < 4; ++r) {
    if (r) __syncthreads();              // round r writes wait for round r-1 reads
#pragma unroll
    for (int mm = 0; mm < 2; ++mm)
#pragma unroll
      for (int nt2 = 0; nt2 < 2; ++nt2)
        *reinterpret_cast<f32x4*>(red + (mm * 4 + kq) * 1024 +
                                  (nh * 32 + nt2 * 16 + r16) * 16 + q * 4) = acc[2 * r + mm][nt2];
    __syncthreads();
    {
      const int mm_r = wv >> 2;          // reducer role: m-tile parity
      const int oq = wv & 3;             // o quarter
      const int pxl = lane >> 2;         // 0..15
      const int o4 = oq * 16 + (lane & 3) * 4;
      f32x4 ssum = {};
#pragma unroll
      for (int kk = 0; kk < 4; ++kk) {
        const float* rb = red + (mm_r * 4 + kk) * 1024;
#pragma unroll
        for (int i = 0; i < 4; ++i)
          ssum[i] += rb[(o4 + i) * 16 + pxl];
      }
      long px = pxbase + (2 * r + mm_r) * 16 + pxl;   // D layout row=q*4+b folded via px_local
      *reinterpret_cast<f32x4*>(out + px * 64 + o4) = ssum;
    }
  }
}

extern "C" void kernel_launch(void* const* d_in, const int* in_sizes, int n_in,
                              void* d_out, int out_size, void* d_ws, size_t ws_size,
                              hipStream_t stream) {
  const float* x = (const float*)d_in[0];
  const float* W = (const float*)d_in[1];
  float* out = (float*)d_out;
  unsigned short* Wp = (unsigned short*)d_ws;   // 288 KB packed fragment-linear bf16 W

  hipLaunchKernelGGL(wprep_kernel, dim3(576), dim3(256), 0, stream, W, Wp);
  hipLaunchKernelGGL(quad_kernel, dim3(256), dim3(512), 0, stream, x, Wp, out);
}